// Round 8
// baseline (449.803 us; speedup 1.0000x reference)
//
#include <hip/hip_runtime.h>
#include <hip/hip_bf16.h>

// TransformerLayer (Swin shifted-window attention + MLP), fp32 I/O, MI355X.
// R15: gemm_bt gets the flash-proven 2-phase counted-vmcnt pipeline:
// double-buffered As/Bs (2x16KB each, LDS 64KB -> 2 blocks/CU); per K-step
// STAGE(buf^1,next) -> s_waitcnt vmcnt(8) -> s_barrier -> 32 MFMA ->
// s_barrier. No vmcnt(0) drain in the loop (was: __syncthreads drained all
// 8 staging loads serially every K-step). BK=64 + XOR-granule swizzle
// (conflict-free, R14-verified: SQ_LDS_BANK_CONFLICT=0) retained.
// Flash unchanged (R3 structure, verified 79.6us).
// Phases:
//  0. cvtw weights+mask->D ; cvt target->d_out.lo ; cvt source->d_out.hi
//  1. vw=QKV(tgt,Wv)->RB ; vwT=transpose->RC ; kw=QKV(tgt,Wk)->RB ; qw=QKV(src,Wq)->RA
//  2. flash_attn(qw,kw,vwT,mask16) -> msg (bf16, d_out.lo)
//  3. msg@Wm^T->RB ; LN1->RC
//  4. MLP1(src16|msg_ln,W1,gelu)->hid ; MLP2(hid,W2)->RB   (slabbed if small ws)
//  5. LN2(RB)+source(fp32) -> d_out fp32

using bf16 = __hip_bfloat16;
typedef __attribute__((ext_vector_type(8))) short short8;
typedef __attribute__((ext_vector_type(4))) float f32x4;

__device__ __forceinline__ float bf2f(unsigned short b) {
    return __uint_as_float(((unsigned)b) << 16);
}
__device__ __forceinline__ unsigned short f2bf(float f) {
    unsigned u = __float_as_uint(f);
    unsigned r = (u + 0x7FFFu + ((u >> 16) & 1u)) >> 16;
    return (unsigned short)r;
}
__device__ __forceinline__ void cp16(const void* g, void* l) {
    __builtin_amdgcn_global_load_lds((const __attribute__((address_space(1))) void*)g,
                                     (__attribute__((address_space(3))) void*)l,
                                     16, 0, 0);
}
__device__ __forceinline__ float fast_gelu(float v) {
    const float z = v * (0.7978845608028654f + 0.0356774081f * v * v);
    const float t = 1.f - 2.f / (__expf(2.f * z) + 1.f);
    return 0.5f * v * (1.f + t);
}

constexpr int MODE_PLAIN = 0;
constexpr int MODE_QKV   = 1;  // store bf16 at roll(-16)+window-permuted row
constexpr int MODE_GELU  = 3;  // fast gelu then bf16 store

// C[M,N] = A[M,K] @ B[N,K]^T ; bf16 operands, fp32 acc. 128x128 tile,
// BK=64, XOR-granule-swizzled double-buffered LDS, counted-vmcnt pipeline.
// nlog >= 0: 1-D grid, XCD-aware remap; nlog < 0: plain 2-D grid.
// K must be a multiple of 64 (call sites: 256/512/2048).
template<int MODE, bool CONCAT>
__global__ __launch_bounds__(256)
void gemm_bt(const bf16* __restrict__ A, const bf16* __restrict__ A2,
             const bf16* __restrict__ Bm, void* __restrict__ C,
             int K, int ldc, long sAz, long sBz, int nlog)
{
    __shared__ __align__(16) bf16 As[2][128 * 64];   // 2 x 16 KB
    __shared__ __align__(16) bf16 Bs[2][128 * 64];   // 2 x 16 KB

    const int z = blockIdx.z;
    A  += (long)z * sAz;
    Bm += (long)z * sBz;

    const int tid  = threadIdx.x;
    const int wave = tid >> 6, lane = tid & 63;
    const int wm = wave >> 1, wn = wave & 1;
    const int quad = lane >> 4, lrow = lane & 15;

    int m0, n0;
    if (nlog >= 0) {
        const int lin = blockIdx.x;
        const int xcd = lin & 7;
        const int s   = lin >> 3;
        const int ni  = s & ((1 << nlog) - 1);
        const int mi  = ((s >> nlog) << 3) | xcd;
        m0 = mi * 128; n0 = ni * 128;
    } else {
        m0 = blockIdx.x * 128; n0 = blockIdx.y * 128;
    }

    // hoisted staging coords: granule li = i*256+tid over [128 rows][8 g]
    int srow[4], sgo[4], lofs[4];
#pragma unroll
    for (int i = 0; i < 4; ++i) {
        const int li = i * 256 + tid;
        srow[i] = li >> 3;
        sgo[i]  = (((li & 7) ^ srow[i]) & 7) << 3;
        lofs[i] = li << 3;
    }

    f32x4 acc[4][4];
#pragma unroll
    for (int i = 0; i < 4; i++)
#pragma unroll
        for (int j = 0; j < 4; j++) acc[i][j] = (f32x4){0.f, 0.f, 0.f, 0.f};

    // STAGE: 8 cp16 (4 A + 4 B) into buffer b for K-offset k0
#define STAGE_TILE(b, k0s)                                                     \
    do {                                                                       \
        _Pragma("unroll")                                                      \
        for (int i = 0; i < 4; ++i) {                                          \
            const bf16* ga;                                                    \
            if (CONCAT) {                                                      \
                ga = ((k0s) < 256)                                             \
                   ? (A  + (long)(m0 + srow[i]) * 256 + (k0s) + sgo[i])        \
                   : (A2 + (long)(m0 + srow[i]) * 256 + ((k0s) - 256) + sgo[i]);\
            } else {                                                           \
                ga = A + (long)(m0 + srow[i]) * K + (k0s) + sgo[i];            \
            }                                                                  \
            cp16(ga, &As[b][lofs[i]]);                                         \
            const bf16* gb = Bm + (long)(n0 + srow[i]) * K + (k0s) + sgo[i];   \
            cp16(gb, &Bs[b][lofs[i]]);                                         \
        }                                                                      \
    } while (0)

    STAGE_TILE(0, 0);
    __builtin_amdgcn_sched_barrier(0);

    int buf = 0;
    for (int k0 = 0; k0 < K; k0 += 64) {
        const int nxt = (k0 + 64 < K) ? (k0 + 64) : 0;   // wrap: harmless
        STAGE_TILE(buf ^ 1, nxt);
        __builtin_amdgcn_sched_barrier(0);

        // retire THIS tile's 8 stages; leave next 8 in flight
        asm volatile("s_waitcnt vmcnt(8)" ::: "memory");
        __builtin_amdgcn_sched_barrier(0);
        __builtin_amdgcn_s_barrier();        // all waves' tile(k0) visible
        __builtin_amdgcn_sched_barrier(0);

        const bf16* Ab = As[buf];
        const bf16* Bb = Bs[buf];
        __builtin_amdgcn_s_setprio(1);
#pragma unroll
        for (int sl = 0; sl < 2; ++sl) {     // two 32-K slices
            short8 af[4], bfv[4];
#pragma unroll
            for (int i = 0; i < 4; i++) {
                const int ra = wm * 64 + i * 16 + lrow;
                const int rb = wn * 64 + i * 16 + lrow;
                const int h  = (sl << 2) + quad;
                af[i]  = *(const short8*)(Ab + ra * 64 + (((h ^ ra) & 7) << 3));
                bfv[i] = *(const short8*)(Bb + rb * 64 + (((h ^ rb) & 7) << 3));
            }
#pragma unroll
            for (int i = 0; i < 4; i++)
#pragma unroll
                for (int j = 0; j < 4; j++)
                    acc[i][j] = __builtin_amdgcn_mfma_f32_16x16x32_bf16(
                        af[i], bfv[j], acc[i][j], 0, 0, 0);
        }
        __builtin_amdgcn_s_setprio(0);

        __builtin_amdgcn_sched_barrier(0);
        __builtin_amdgcn_s_barrier();        // reads of buf done before overwrite
        __builtin_amdgcn_sched_barrier(0);
        buf ^= 1;
    }
#undef STAGE_TILE

    // C/D layout: col = lane&15, row = quad*4 + reg (m89/m91 verified)
    unsigned short* outb = (unsigned short*)C;
    if (MODE == MODE_QKV) {
#pragma unroll
        for (int i = 0; i < 4; i++)
#pragma unroll
            for (int j = 0; j < 4; j++)
#pragma unroll
                for (int r = 0; r < 4; r++) {
                    const int gm = m0 + wm * 64 + i * 16 + quad * 4 + r;
                    const int gn = n0 + wn * 64 + j * 16 + lrow;
                    const int batch = gm >> 12, pos = gm & 4095;
                    const int ii = pos >> 6, jj = pos & 63;
                    const int ri = (ii + 48) & 63, rj = (jj + 48) & 63; // roll(-16)
                    const long prow =
                        ((long)((batch << 2) + ((ri >> 5) << 1) + (rj >> 5)) << 10)
                        + ((ri & 31) << 5) + (rj & 31);
                    outb[prow * 256 + gn] = f2bf(acc[i][j][r]);
                }
    } else {
#pragma unroll
        for (int i = 0; i < 4; i++)
#pragma unroll
            for (int j = 0; j < 4; j++)
#pragma unroll
                for (int r = 0; r < 4; r++) {
                    const int gm = m0 + wm * 64 + i * 16 + quad * 4 + r;
                    const int gn = n0 + wn * 64 + j * 16 + lrow;
                    float v = acc[i][j][r];
                    if (MODE == MODE_GELU) v = fast_gelu(v);
                    outb[(long)gm * ldc + gn] = f2bf(v);
                }
    }
}

// stage one 32-key tile: K[32x256] XOR-granule-swizzled, V^T[256x32] linear.
// 8 cp16/thread (K 4 + V 4), issued back-to-back, counted by vmcnt.
__device__ __forceinline__ void stage_kv(const bf16* __restrict__ Kp,
                                         const bf16* __restrict__ Vp,
                                         bf16* ksl, bf16* vsl,
                                         int kb0, int tid)
{
#pragma unroll
    for (int i = 0; i < 4; ++i) {
        const int li = i * 256 + tid;            // granule id over [32][32]
        const int key = li >> 5, g = li & 31;
        const int sg = (g & 24) | ((g ^ key) & 7);
        cp16(Kp + (long)(kb0 + key) * 256 + (sg << 3), ksl + (li << 3));
    }
#pragma unroll
    for (int i = 0; i < 4; ++i) {
        const int li = i * 256 + tid;            // granule id over [256][4]
        const int ch = li >> 2, g = li & 3;
        cp16(Vp + ((long)ch << 10) + kb0 + (g << 3), vsl + (li << 3));
    }
}

// Flash attention (verified Round-3 structure, 79.6us): one (window, 64-row
// q-block) per block; 4 waves x 16 rows, wave-local softmax. 2-phase
// counted-vmcnt pipeline over 32 tiles of 32 keys. No-max softmax.
__global__ __launch_bounds__(256)
void flash_attn(const bf16* __restrict__ Q, const bf16* __restrict__ Kw,
                const bf16* __restrict__ VT, const bf16* __restrict__ mask16,
                bf16* __restrict__ msg)
{
    __shared__ __align__(16) bf16 Ks[2 * 32 * 256];          // 2 x 16 KB
    __shared__ __align__(16) bf16 Vs[2 * 256 * 32];          // 2 x 16 KB
    __shared__ __align__(16) unsigned short Pm[4][16 * 32];  // 4 KB

    // remap: XCD c = f&7 gets windows {c, 8+c, 16+c, 24+c} (same mask type).
    const int f   = blockIdx.x;
    const int win = (f & 7) | ((f >> 7) << 3);
    const int qb  = (f >> 3) & 15;
    const int m0  = qb << 6;

    const bf16* Qp = Q  + ((long)win << 18);
    const bf16* Kp = Kw + ((long)win << 18);
    const bf16* Vp = VT + ((long)win << 18);
    const unsigned short* mk =
        (const unsigned short*)mask16 + ((long)(win & 3) << 20);

    const int tid = threadIdx.x;
    const int wave = tid >> 6, lane = tid & 63;
    const int quad = lane >> 4, lrow = lane & 15;
    unsigned short* Pw = Pm[wave];

    // Q A-frags: row = m0 + wave*16 + lrow, all 256 ch.
    short8 qf[8];
    {
        const bf16* qr = Qp + (long)(m0 + (wave << 4) + lrow) * 256 + quad * 8;
#pragma unroll
        for (int kc = 0; kc < 8; ++kc) qf[kc] = *(const short8*)(qr + kc * 32);
    }

    f32x4 o[16];
#pragma unroll
    for (int nf = 0; nf < 16; ++nf) o[nf] = (f32x4){0.f, 0.f, 0.f, 0.f};
    float l_lane[4] = {0.f, 0.f, 0.f, 0.f};

    stage_kv(Kp, Vp, Ks, Vs, 0, tid);            // prologue: tile 0 -> buf 0

    const int mrow = m0 + (wave << 4) + (quad << 2);

    for (int kt = 0; kt < 32; ++kt) {
        const int cur = kt & 1;
        const int kb0 = kt << 5;

        // mask loads for this tile (8 scalar ushorts, consumed after QK^T)
        unsigned short mreg[2][4];
#pragma unroll
        for (int r = 0; r < 4; ++r)
#pragma unroll
            for (int nf = 0; nf < 2; ++nf)
                mreg[nf][r] = mk[((long)(mrow + r) << 10)
                                 | (kb0 + (nf << 4) + lrow)];

        // stage next tile into the other buffer (wraps at 31; harmless)
        const int nxt = ((kt + 1) & 31) << 5;
        stage_kv(Kp, Vp, Ks + (cur ^ 1) * 8192, Vs + (cur ^ 1) * 8192, nxt, tid);

        // wait for THIS tile's 8 stages (leave next-8 + mask-8 in flight)
        asm volatile("s_waitcnt vmcnt(16)" ::: "memory");
        __builtin_amdgcn_sched_barrier(0);
        __builtin_amdgcn_s_barrier();
        __builtin_amdgcn_sched_barrier(0);

        // ---- QK^T: s[nf], keys nf*16+lrow ----
        f32x4 s[2];
        s[0] = (f32x4){0.f, 0.f, 0.f, 0.f};
        s[1] = (f32x4){0.f, 0.f, 0.f, 0.f};
        const bf16* kbase = Ks + cur * 8192;
        __builtin_amdgcn_s_setprio(1);
#pragma unroll
        for (int nf = 0; nf < 2; ++nf) {
            const int key = (nf << 4) + lrow;
            short8 kb[8];
#pragma unroll
            for (int kc = 0; kc < 8; ++kc) {
                const int g = (kc << 2) + quad;
                const int sg = (g & 24) | ((g ^ key) & 7);
                kb[kc] = *(const short8*)(kbase + (key << 8) + (sg << 3));
            }
#pragma unroll
            for (int kc = 0; kc < 8; ++kc)
                s[nf] = __builtin_amdgcn_mfma_f32_16x16x32_bf16(
                    qf[kc], kb[kc], s[nf], 0, 0, 0);
        }
        __builtin_amdgcn_s_setprio(0);

        // ---- no-max softmax: e = exp(s/16 + mask); P bf16 -> wave LDS ----
#pragma unroll
        for (int r = 0; r < 4; ++r) {
            const int prow = (quad << 2) + r;
#pragma unroll
            for (int nf = 0; nf < 2; ++nf) {
                const float e = __expf(s[nf][r] * 0.0625f + bf2f(mreg[nf][r]));
                l_lane[r] += e;
                Pw[(prow << 5) + (nf << 4) + lrow] = f2bf(e);
            }
        }
        asm volatile("s_waitcnt lgkmcnt(0)" ::: "memory");
        __builtin_amdgcn_sched_barrier(0);

        // ---- PV: O[16x256] += P[16x32] @ V[32x256] ----
        const short8 af = *(const short8*)((const unsigned short*)Pw
                                           + (lrow << 5) + (quad << 3));
        const bf16* vbase = Vs + cur * 8192;
        __builtin_amdgcn_s_setprio(1);
#pragma unroll
        for (int nf = 0; nf < 16; ++nf) {
            const int vc = (nf << 4) + lrow;
            const short8 bfv = *(const short8*)(vbase + (vc << 5) + (quad << 3));
            o[nf] = __builtin_amdgcn_mfma_f32_16x16x32_bf16(af, bfv, o[nf], 0, 0, 0);
        }
        __builtin_amdgcn_s_setprio(0);

        __builtin_amdgcn_sched_barrier(0);
        __builtin_amdgcn_s_barrier();   // all waves done reading cur buffers
        __builtin_amdgcn_sched_barrier(0);
    }

    // ---- epilogue: reduce l over lrow, normalize, de-window + inv-roll ----
    float l[4];
#pragma unroll
    for (int r = 0; r < 4; ++r) {
        float v = l_lane[r];
#pragma unroll
        for (int off = 1; off < 16; off <<= 1) v += __shfl_xor(v, off, 64);
        l[r] = v;
    }
    const int batch = win >> 2;
    const int s1 = (win >> 1) & 1, s2 = win & 1;
    unsigned short* outb = (unsigned short*)msg;
#pragma unroll
    for (int r = 0; r < 4; ++r) {
        const float inv = 1.f / l[r];
        const int gm = m0 + (wave << 4) + (quad << 2) + r;
        const int r5 = gm >> 5, c5 = gm & 31;
        const int ii = ((s1 << 5) + r5 + 16) & 63;
        const int jj = ((s2 << 5) + c5 + 16) & 63;
        const long mr = (long)batch * 4096 + ii * 64 + jj;
#pragma unroll
        for (int nf = 0; nf < 16; ++nf) {
            const int gn = (nf << 4) + lrow;
            outb[mr * 256 + gn] = f2bf(o[nf][r] * inv);
        }
    }
}

// merged conversion: 6 weights + mask, segments by blockIdx.y
__global__ __launch_bounds__(256)
void cvtw_k(const float* __restrict__ w0, const float* __restrict__ w1,
            const float* __restrict__ w2, const float* __restrict__ w3,
            const float* __restrict__ w4, const float* __restrict__ w5,
            const float* __restrict__ w6, unsigned short* __restrict__ d)
{
    const float* s; long n4, off4;
    switch (blockIdx.y) {
    case 0:  s = w0; n4 = 16384;   off4 = 0;      break;
    case 1:  s = w1; n4 = 16384;   off4 = 16384;  break;
    case 2:  s = w2; n4 = 16384;   off4 = 32768;  break;
    case 3:  s = w3; n4 = 16384;   off4 = 49152;  break;
    case 4:  s = w4; n4 = 262144;  off4 = 65536;  break;
    case 5:  s = w5; n4 = 131072;  off4 = 327680; break;
    default: s = w6; n4 = 1048576; off4 = 458752; break;  // mask
    }
    ushort4* dst = (ushort4*)d + off4;
    for (long i = (long)blockIdx.x * 256 + threadIdx.x; i < n4;
         i += (long)gridDim.x * 256) {
        const float4 v = ((const float4*)s)[i];
        ushort4 o;
        o.x = f2bf(v.x); o.y = f2bf(v.y); o.z = f2bf(v.z); o.w = f2bf(v.w);
        dst[i] = o;
    }
}

__global__ __launch_bounds__(256)
void cvt_k(const float* __restrict__ s, unsigned short* __restrict__ d, long n4)
{
    for (long i = (long)blockIdx.x * 256 + threadIdx.x; i < n4;
         i += (long)gridDim.x * 256) {
        const float4 v = ((const float4*)s)[i];
        ushort4 o;
        o.x = f2bf(v.x); o.y = f2bf(v.y); o.z = f2bf(v.z); o.w = f2bf(v.w);
        ((ushort4*)d)[i] = o;
    }
}

// vwT[win][c][s] = vw[win][s][c], 64x64 LDS tiles
__global__ __launch_bounds__(256)
void transpose_vw(const bf16* __restrict__ vw, bf16* __restrict__ vwT)
{
    __shared__ bf16 t[64][65];
    const int win = blockIdx.z;
    const int s0 = blockIdx.x * 64, c0 = blockIdx.y * 64;
    const bf16* src = vw  + ((long)win << 18);
    bf16*       dst = vwT + ((long)win << 18);
    const int tid = threadIdx.x;
#pragma unroll
    for (int ii = 0; ii < 16; ++ii) {
        const int lin = ii * 256 + tid;
        const int r = lin >> 6, c = lin & 63;
        t[r][c] = src[(long)(s0 + r) * 256 + c0 + c];
    }
    __syncthreads();
#pragma unroll
    for (int ii = 0; ii < 16; ++ii) {
        const int lin = ii * 256 + tid;
        const int r = lin >> 6, c = lin & 63;
        dst[(long)(c0 + r) * 1024 + s0 + c] = t[c][r];
    }
}

// LN1: bf16 in -> bf16 out, fp32 gamma/beta. One 256-ch row per wave.
__global__ __launch_bounds__(256)
void ln1_k(const bf16* __restrict__ x, const float* __restrict__ g,
           const float* __restrict__ be, bf16* __restrict__ out)
{
    const int wave = threadIdx.x >> 6, lane = threadIdx.x & 63;
    const long row = (long)blockIdx.x * 4 + wave;
    const ushort4 u = ((const ushort4*)((const unsigned short*)x + (row << 8)))[lane];
    const float v0 = bf2f(u.x), v1 = bf2f(u.y), v2 = bf2f(u.z), v3 = bf2f(u.w);
    float s = v0 + v1 + v2 + v3;
    float q = v0 * v0 + v1 * v1 + v2 * v2 + v3 * v3;
#pragma unroll
    for (int o = 1; o < 64; o <<= 1) { s += __shfl_xor(s, o, 64); q += __shfl_xor(q, o, 64); }
    const float mean = s * 0.00390625f;
    const float var  = q * 0.00390625f - mean * mean;
    const float inv  = rsqrtf(fmaxf(var, 0.f) + 1e-5f);
    const float4 gg = ((const float4*)g)[lane];
    const float4 bb = ((const float4*)be)[lane];
    ushort4 o4;
    o4.x = f2bf((v0 - mean) * inv * gg.x + bb.x);
    o4.y = f2bf((v1 - mean) * inv * gg.y + bb.y);
    o4.z = f2bf((v2 - mean) * inv * gg.z + bb.z);
    o4.w = f2bf((v3 - mean) * inv * gg.w + bb.w);
    ((ushort4*)((unsigned short*)out + (row << 8)))[lane] = o4;
}

// LN2 + residual: bf16 in, fp32 gamma/beta/residual, fp32 out.
__global__ __launch_bounds__(256)
void ln2_k(const bf16* __restrict__ x, const float* __restrict__ g,
           const float* __restrict__ be, const float* __restrict__ res,
           float* __restrict__ out)
{
    const int wave = threadIdx.x >> 6, lane = threadIdx.x & 63;
    const long row = (long)blockIdx.x * 4 + wave;
    const ushort4 u = ((const ushort4*)((const unsigned short*)x + (row << 8)))[lane];
    const float v0 = bf2f(u.x), v1 = bf2f(u.y), v2 = bf2f(u.z), v3 = bf2f(u.w);
    float s = v0 + v1 + v2 + v3;
    float q = v0 * v0 + v1 * v1 + v2 * v2 + v3 * v3;
#pragma unroll
    for (int o = 1; o < 64; o <<= 1) { s += __shfl_xor(s, o, 64); q += __shfl_xor(q, o, 64); }
    const float mean = s * 0.00390625f;
    const float var  = q * 0.00390625f - mean * mean;
    const float inv  = rsqrtf(fmaxf(var, 0.f) + 1e-5f);
    const float4 gg = ((const float4*)g)[lane];
    const float4 bb = ((const float4*)be)[lane];
    const float4 rr = ((const float4*)(res + (row << 8)))[lane];
    float4 o4;
    o4.x = (v0 - mean) * inv * gg.x + bb.x + rr.x;
    o4.y = (v1 - mean) * inv * gg.y + bb.y + rr.y;
    o4.z = (v2 - mean) * inv * gg.z + bb.z + rr.z;
    o4.w = (v3 - mean) * inv * gg.w + bb.w + rr.w;
    ((float4*)(out + (row << 8)))[lane] = o4;
}

extern "C" void kernel_launch(void* const* d_in, const int* in_sizes, int n_in,
                              void* d_out, int out_size, void* d_ws, size_t ws_size,
                              hipStream_t stream)
{
    const float* source = (const float*)d_in[0];
    const float* target = (const float*)d_in[1];
    const float* mask   = (const float*)d_in[2];
    const float* Wq = (const float*)d_in[3];
    const float* Wk = (const float*)d_in[4];
    const float* Wv = (const float*)d_in[5];
    const float* Wm = (const float*)d_in[6];
    const float* ln1g = (const float*)d_in[7];
    const float* ln1b = (const float*)d_in[8];
    const float* W1 = (const float*)d_in[9];
    const float* W2 = (const float*)d_in[10];
    const float* ln2g = (const float*)d_in[11];
    const float* ln2b = (const float*)d_in[12];
    float* out = (float*)d_out;

    char* ws = (char*)d_ws;
    const size_t MB = 1ull << 20;

    bf16* RA = (bf16*)(ws +  0 * MB);   // qw (-> src16 in slab path)
    bf16* RB = (bf16*)(ws + 16 * MB);   // vw -> kw -> msg_mm -> mlp_out
    bf16* RC = (bf16*)(ws + 32 * MB);   // vwT -> msg_ln
    unsigned short* D = (unsigned short*)(ws + 48 * MB);  // weights+mask bf16
    bf16* Wq16 = (bf16*)(D);
    bf16* Wk16 = (bf16*)(D + 65536);
    bf16* Wv16 = (bf16*)(D + 131072);
    bf16* Wm16 = (bf16*)(D + 196608);
    bf16* W116 = (bf16*)(D + 262144);
    bf16* W216 = (bf16*)(D + 1310720);
    bf16* mask16 = (bf16*)(D + 1835008);
    // d_out (33.55 MB) phased scratch:
    bf16* tgt16 = (bf16*)d_out;                       // [0, 16.78 MB)
    bf16* src16 = (bf16*)((char*)d_out + 16777216);   // [16.78, 33.55 MB)
    bf16* msgb  = (bf16*)d_out;                       // flash output (16.78 MB)

    const bool bigws = ws_size >= (200ull << 20);     // 64MB + 134.3MB hid
    bf16* hidbig = (bf16*)(ws + 64 * MB);

    // 0) weights + mask + activations -> bf16
    cvtw_k<<<dim3(256, 7), 256, 0, stream>>>(Wq, Wk, Wv, Wm, W1, W2, mask, D);
    cvt_k<<<4096, 256, 0, stream>>>(target, (unsigned short*)tgt16, 2097152);
    cvt_k<<<4096, 256, 0, stream>>>(source, (unsigned short*)src16, 2097152);

    // 1) projections (roll+window-permuted store) + V transpose
    gemm_bt<MODE_QKV, false><<<dim3(512, 1, 1), 256, 0, stream>>>(
        tgt16, nullptr, Wv16, RB, 256, 256, 0, 0, 1);
    transpose_vw<<<dim3(16, 4, 32), 256, 0, stream>>>(RB, RC);
    gemm_bt<MODE_QKV, false><<<dim3(512, 1, 1), 256, 0, stream>>>(
        tgt16, nullptr, Wk16, RB, 256, 256, 0, 0, 1);
    gemm_bt<MODE_QKV, false><<<dim3(512, 1, 1), 256, 0, stream>>>(
        src16, nullptr, Wq16, RA, 256, 256, 0, 0, 1);

    // 2) fused flash attention: 32 win x 16 q-blocks, msg -> d_out.lo (bf16)
    flash_attn<<<dim3(512), 256, 0, stream>>>(RA, RB, RC, mask16, msgb);

    // 3) msg @ Wm^T -> RB ; LN1 -> RC
    gemm_bt<MODE_PLAIN, false><<<dim3(512, 1, 1), 256, 0, stream>>>(
        msgb, nullptr, Wm16, RB, 256, 256, 0, 0, 1);
    ln1_k<<<8192, 256, 0, stream>>>(RB, ln1g, ln1b, RC);

    if (bigws) {
        // 4) MLP unslabbed: src16 stays valid in d_out.hi; hid 134MB in ws.
        // 1-D XCD remap: MLP1 nlog=4 (16 n-blocks), MLP2 nlog=1.
        gemm_bt<MODE_GELU, true><<<dim3(4096, 1, 1), 256, 0, stream>>>(
            src16, RC, W116, hidbig, 512, 2048, 0, 0, 4);
        gemm_bt<MODE_PLAIN, false><<<dim3(512, 1, 1), 256, 0, stream>>>(
            hidbig, nullptr, W216, RB, 2048, 256, 0, 0, 1);
    } else {
        // 4) slab path: re-convert source into RA, hid in d_out
        bf16* hid = (bf16*)d_out;
        cvt_k<<<8192, 256, 0, stream>>>(source, (unsigned short*)RA, 2097152);
        for (int sl = 0; sl < 4; ++sl) {
            const long ro = (long)sl * 8192 * 256;
            gemm_bt<MODE_GELU, true><<<dim3(64, 16, 1), 256, 0, stream>>>(
                RA + ro, RC + ro, W116, hid, 512, 2048, 0, 0, -1);
            gemm_bt<MODE_PLAIN, false><<<dim3(64, 2, 1), 256, 0, stream>>>(
                hid, nullptr, W216, RB + ro, 2048, 256, 0, 0, -1);
        }
    }

    // 5) LN2 + fp32 residual -> d_out
    ln2_k<<<8192, 256, 0, stream>>>(RB, ln2g, ln2b, source, out);
}